// Round 2
// baseline (747.892 us; speedup 1.0000x reference)
//
#include <hip/hip_runtime.h>
#include <hip/hip_bf16.h>

// GN block on MI355X — FP32 inputs/outputs (per reference dtypes).
//
// Decomposition: We = [We0; We1; We2; We3] (rows 0:128 edge, 128:256 recv,
// 256:384 send, 384:512 u). Precompute P1=node@We1, P2=node@We2, Pv=node@Wv1
// (stored bf16), ce = u@We3+be, cv = u@Wv2+bv. Then:
//   e_new = relu(edge_attr@We0 + P1[recv] + P2[send] + ce)
//   aggr  = CSR-gather-sum of e_new by receiver
//   v_new = relu(aggr@Wv0 + Pv + cv)
//   u_new = relu([mean_e, mean_v, u]@Wu + bu)
// Weights cast to bf16 in LDS only (abs err ~1e-2 << 0.62 threshold).

#define NN 20000
#define NE 320000
#define DD 128

typedef unsigned short u16;

__device__ __forceinline__ float b2f(unsigned short h) {
  return __uint_as_float(((unsigned int)h) << 16);
}
__device__ __forceinline__ unsigned short f2b(float f) {
  unsigned int u = __float_as_uint(f);
  unsigned int r = (u + 0x7fffu + ((u >> 16) & 1u)) >> 16;  // RNE
  return (unsigned short)r;
}

// ---------------------------------------------------------------- constants
__global__ void k_const(const float* u, const float* We, const float* be,
                        const float* Wv, const float* bv, float* ce,
                        float* cv) {
  __shared__ float su[DD];
  int j = threadIdx.x;  // 128 threads
  su[j] = u[j];
  __syncthreads();
  float a = be[j];
  float b = bv[j];
  for (int k = 0; k < DD; ++k) {
    a = fmaf(su[k], We[(384 + k) * DD + j], a);
    b = fmaf(su[k], Wv[(256 + k) * DD + j], b);
  }
  ce[j] = a;
  cv[j] = b;
}

// ---------------------------------------------------------------- CSR build
__global__ void k_hist(const int* recv, int* counts) {
  int e = blockIdx.x * blockDim.x + threadIdx.x;
  if (e < NE) atomicAdd(&counts[recv[e]], 1);
}

__global__ void k_scan(const int* counts, int* rowptr, int* cursor) {
  __shared__ int buf[256];
  __shared__ int carry;
  int tid = threadIdx.x;
  if (tid == 0) carry = 0;
  __syncthreads();
  for (int base = 0; base < NN; base += 256) {
    int i = base + tid;
    int v = (i < NN) ? counts[i] : 0;
    buf[tid] = v;
    __syncthreads();
    for (int off = 1; off < 256; off <<= 1) {  // Hillis-Steele inclusive
      int t = (tid >= off) ? buf[tid - off] : 0;
      __syncthreads();
      buf[tid] += t;
      __syncthreads();
    }
    int incl = buf[tid];
    int excl = incl - v;
    if (i < NN) {
      int r = carry + excl;
      rowptr[i] = r;
      cursor[i] = r;
    }
    __syncthreads();
    if (tid == 255) carry += incl;
    __syncthreads();
  }
  if (tid == 0) rowptr[NN] = carry;  // == NE
}

__global__ void k_fill(const int* recv, int* cursor, int* elist) {
  int e = blockIdx.x * blockDim.x + threadIdx.x;
  if (e < NE) {
    int slot = atomicAdd(&cursor[recv[e]], 1);
    elist[slot] = e;
  }
}

// ----------------------------------------------- P = node_attr @ {We1,We2,Wv1}
__global__ __launch_bounds__(256) void k_nodeproj(const float* node_attr,
                                                  const float* We,
                                                  const float* Wv, u16* P1,
                                                  u16* P2, u16* Pv) {
  __shared__ float sA[64 * DD];  // 32 KB fp32 A-tile
  __shared__ u16 sWh[DD * DD];   // 32 KB bf16 weights
  const float* W = (blockIdx.y == 0) ? (We + 128 * DD)
                 : (blockIdx.y == 1) ? (We + 256 * DD)
                                     : (Wv + 128 * DD);
  u16* P = (blockIdx.y == 0) ? P1 : (blockIdx.y == 1) ? P2 : Pv;
  int tid = threadIdx.x;
  int n0 = blockIdx.x * 64;
  for (int i = tid; i < DD * DD / 4; i += 256) {
    float4 w4 = ((const float4*)W)[i];
    ushort4 h;
    h.x = f2b(w4.x); h.y = f2b(w4.y); h.z = f2b(w4.z); h.w = f2b(w4.w);
    ((ushort4*)sWh)[i] = h;
  }
  for (int i = tid; i < 64 * DD / 4; i += 256) {
    int n = n0 + (i >> 5);  // 32 float4 per 128-f32 row
    ((float4*)sA)[i] = (n < NN)
                           ? ((const float4*)node_attr)[(size_t)n * 32 + (i & 31)]
                           : make_float4(0, 0, 0, 0);
  }
  __syncthreads();
  int cg = tid & 31, eg = tid >> 5;
  int c0 = cg * 4;
  float acc[8][4] = {};
  for (int k = 0; k < DD; k += 4) {
    float w[4][4];
#pragma unroll
    for (int kk = 0; kk < 4; ++kk) {
      ushort4 wh = *(const ushort4*)&sWh[(k + kk) * DD + c0];
      w[kk][0] = b2f(wh.x); w[kk][1] = b2f(wh.y);
      w[kk][2] = b2f(wh.z); w[kk][3] = b2f(wh.w);
    }
#pragma unroll
    for (int i = 0; i < 8; ++i) {
      float4 a = *(const float4*)&sA[(eg * 8 + i) * DD + k];
      acc[i][0] += a.x * w[0][0] + a.y * w[1][0] + a.z * w[2][0] + a.w * w[3][0];
      acc[i][1] += a.x * w[0][1] + a.y * w[1][1] + a.z * w[2][1] + a.w * w[3][1];
      acc[i][2] += a.x * w[0][2] + a.y * w[1][2] + a.z * w[2][2] + a.w * w[3][2];
      acc[i][3] += a.x * w[0][3] + a.y * w[1][3] + a.z * w[2][3] + a.w * w[3][3];
    }
  }
#pragma unroll
  for (int i = 0; i < 8; ++i) {
    int n = n0 + eg * 8 + i;
    if (n < NN) {
      ushort4 h;
      h.x = f2b(acc[i][0]); h.y = f2b(acc[i][1]);
      h.z = f2b(acc[i][2]); h.w = f2b(acc[i][3]);
      *(ushort4*)&P[(size_t)n * DD + c0] = h;
    }
  }
}

// ------------------------------------------------------------- edge block
__global__ __launch_bounds__(256) void k_edge(const float* edge_attr,
                                              const float* We, const int* recv,
                                              const int* send, const u16* P1,
                                              const u16* P2, const float* ce,
                                              float* e_out, float* sum_e) {
  __shared__ float sA[64 * DD];  // 32 KB
  __shared__ u16 sWh[DD * DD];   // 32 KB -> 64 KB total
  int tid = threadIdx.x;
  int e0 = blockIdx.x * 64;
  for (int i = tid; i < DD * DD / 4; i += 256) {
    float4 w4 = ((const float4*)We)[i];  // rows 0..127
    ushort4 h;
    h.x = f2b(w4.x); h.y = f2b(w4.y); h.z = f2b(w4.z); h.w = f2b(w4.w);
    ((ushort4*)sWh)[i] = h;
  }
  const float4* src = (const float4*)(edge_attr + (size_t)e0 * DD);
  for (int i = tid; i < 64 * DD / 4; i += 256) ((float4*)sA)[i] = src[i];
  __syncthreads();
  int cg = tid & 31, eg = tid >> 5;
  int c0 = cg * 4;
  float acc[8][4] = {};
  for (int k = 0; k < DD; k += 4) {
    float w[4][4];
#pragma unroll
    for (int kk = 0; kk < 4; ++kk) {
      ushort4 wh = *(const ushort4*)&sWh[(k + kk) * DD + c0];
      w[kk][0] = b2f(wh.x); w[kk][1] = b2f(wh.y);
      w[kk][2] = b2f(wh.z); w[kk][3] = b2f(wh.w);
    }
#pragma unroll
    for (int i = 0; i < 8; ++i) {
      float4 a = *(const float4*)&sA[(eg * 8 + i) * DD + k];
      acc[i][0] += a.x * w[0][0] + a.y * w[1][0] + a.z * w[2][0] + a.w * w[3][0];
      acc[i][1] += a.x * w[0][1] + a.y * w[1][1] + a.z * w[2][1] + a.w * w[3][1];
      acc[i][2] += a.x * w[0][2] + a.y * w[1][2] + a.z * w[2][2] + a.w * w[3][2];
      acc[i][3] += a.x * w[0][3] + a.y * w[1][3] + a.z * w[2][3] + a.w * w[3][3];
    }
  }
  __syncthreads();   // done with sA/sWh
  float* sCol = sA;  // reuse LDS for per-block column sums
  if (tid < DD) sCol[tid] = 0.f;
  __syncthreads();
  float4 cef = *(const float4*)&ce[c0];
  float cs0 = 0, cs1 = 0, cs2 = 0, cs3 = 0;
#pragma unroll
  for (int i = 0; i < 8; ++i) {
    int e = e0 + eg * 8 + i;
    int r = recv[e], s = send[e];
    ushort4 p1h = *(const ushort4*)&P1[(size_t)r * DD + c0];
    ushort4 p2h = *(const ushort4*)&P2[(size_t)s * DD + c0];
    float v0 = fmaxf(acc[i][0] + b2f(p1h.x) + b2f(p2h.x) + cef.x, 0.f);
    float v1 = fmaxf(acc[i][1] + b2f(p1h.y) + b2f(p2h.y) + cef.y, 0.f);
    float v2 = fmaxf(acc[i][2] + b2f(p1h.z) + b2f(p2h.z) + cef.z, 0.f);
    float v3 = fmaxf(acc[i][3] + b2f(p1h.w) + b2f(p2h.w) + cef.w, 0.f);
    *(float4*)&e_out[(size_t)e * DD + c0] = make_float4(v0, v1, v2, v3);
    cs0 += v0; cs1 += v1; cs2 += v2; cs3 += v3;
  }
  atomicAdd(&sCol[c0 + 0], cs0);
  atomicAdd(&sCol[c0 + 1], cs1);
  atomicAdd(&sCol[c0 + 2], cs2);
  atomicAdd(&sCol[c0 + 3], cs3);
  __syncthreads();
  if (tid < DD) atomicAdd(&sum_e[tid], sCol[tid]);
}

// ----------------------------------------------------- aggregation (CSR sum)
__global__ void k_aggr(const float* e_new, const int* rowptr, const int* elist,
                       float* aggr) {
  int n = blockIdx.x;
  int c = threadIdx.x;  // 128
  int b = rowptr[n], e = rowptr[n + 1];
  float s = 0.f;
  for (int i = b; i < e; ++i) s += e_new[(size_t)elist[i] * DD + c];
  aggr[(size_t)n * DD + c] = s;
}

// ------------------------------------------------------------- node block
__global__ __launch_bounds__(256) void k_node(const float* aggr,
                                              const float* Wv, const u16* Pv,
                                              const float* cv, float* v_out,
                                              float* sum_v) {
  __shared__ float sA[64 * DD];
  __shared__ u16 sWh[DD * DD];
  int tid = threadIdx.x;
  int n0 = blockIdx.x * 64;
  for (int i = tid; i < DD * DD / 4; i += 256) {
    float4 w4 = ((const float4*)Wv)[i];  // rows 0..127 (aggr part)
    ushort4 h;
    h.x = f2b(w4.x); h.y = f2b(w4.y); h.z = f2b(w4.z); h.w = f2b(w4.w);
    ((ushort4*)sWh)[i] = h;
  }
  for (int i = tid; i < 64 * DD / 4; i += 256) {
    int n = n0 + (i >> 5);
    ((float4*)sA)[i] = (n < NN) ? ((const float4*)aggr)[(size_t)n * 32 + (i & 31)]
                                : make_float4(0, 0, 0, 0);
  }
  __syncthreads();
  int cg = tid & 31, eg = tid >> 5;
  int c0 = cg * 4;
  float acc[8][4] = {};
  for (int k = 0; k < DD; k += 4) {
    float w[4][4];
#pragma unroll
    for (int kk = 0; kk < 4; ++kk) {
      ushort4 wh = *(const ushort4*)&sWh[(k + kk) * DD + c0];
      w[kk][0] = b2f(wh.x); w[kk][1] = b2f(wh.y);
      w[kk][2] = b2f(wh.z); w[kk][3] = b2f(wh.w);
    }
#pragma unroll
    for (int i = 0; i < 8; ++i) {
      float4 a = *(const float4*)&sA[(eg * 8 + i) * DD + k];
      acc[i][0] += a.x * w[0][0] + a.y * w[1][0] + a.z * w[2][0] + a.w * w[3][0];
      acc[i][1] += a.x * w[0][1] + a.y * w[1][1] + a.z * w[2][1] + a.w * w[3][1];
      acc[i][2] += a.x * w[0][2] + a.y * w[1][2] + a.z * w[2][2] + a.w * w[3][2];
      acc[i][3] += a.x * w[0][3] + a.y * w[1][3] + a.z * w[2][3] + a.w * w[3][3];
    }
  }
  __syncthreads();
  float* sCol = sA;
  if (tid < DD) sCol[tid] = 0.f;
  __syncthreads();
  float4 cvf = *(const float4*)&cv[c0];
  float cs0 = 0, cs1 = 0, cs2 = 0, cs3 = 0;
#pragma unroll
  for (int i = 0; i < 8; ++i) {
    int n = n0 + eg * 8 + i;
    if (n < NN) {
      ushort4 pvh = *(const ushort4*)&Pv[(size_t)n * DD + c0];
      float v0 = fmaxf(acc[i][0] + b2f(pvh.x) + cvf.x, 0.f);
      float v1 = fmaxf(acc[i][1] + b2f(pvh.y) + cvf.y, 0.f);
      float v2 = fmaxf(acc[i][2] + b2f(pvh.z) + cvf.z, 0.f);
      float v3 = fmaxf(acc[i][3] + b2f(pvh.w) + cvf.w, 0.f);
      *(float4*)&v_out[(size_t)n * DD + c0] = make_float4(v0, v1, v2, v3);
      cs0 += v0; cs1 += v1; cs2 += v2; cs3 += v3;
    }
  }
  atomicAdd(&sCol[c0 + 0], cs0);
  atomicAdd(&sCol[c0 + 1], cs1);
  atomicAdd(&sCol[c0 + 2], cs2);
  atomicAdd(&sCol[c0 + 3], cs3);
  __syncthreads();
  if (tid < DD) atomicAdd(&sum_v[tid], sCol[tid]);
}

// ------------------------------------------------------------ global block
__global__ void k_global(const float* sumbuf, const float* u, const float* Wu,
                         const float* bu, float* out) {
  __shared__ float sin_[384];
  int j = threadIdx.x;  // 128
  sin_[j] = sumbuf[j] * (1.0f / (float)NE);
  sin_[128 + j] = sumbuf[128 + j] * (1.0f / (float)NN);
  sin_[256 + j] = u[j];
  __syncthreads();
  float a = bu[j];
  for (int k = 0; k < 384; ++k) a = fmaf(sin_[k], Wu[k * DD + j], a);
  out[j] = fmaxf(a, 0.f);
}

// ---------------------------------------------------------------- launcher
extern "C" void kernel_launch(void* const* d_in, const int* in_sizes, int n_in,
                              void* d_out, int out_size, void* d_ws,
                              size_t ws_size, hipStream_t stream) {
  const float* edge_attr = (const float*)d_in[0];
  const float* node_attr = (const float*)d_in[1];
  const float* u = (const float*)d_in[2];
  const int* senders = (const int*)d_in[3];
  const int* receivers = (const int*)d_in[4];
  const float* We = (const float*)d_in[5];
  const float* be = (const float*)d_in[6];
  const float* Wv = (const float*)d_in[7];
  const float* bv = (const float*)d_in[8];
  const float* Wu = (const float*)d_in[9];
  const float* bu = (const float*)d_in[10];

  float* e_out = (float*)d_out;
  float* v_out = e_out + (size_t)NE * DD;
  float* u_out = v_out + (size_t)NN * DD;

  // workspace layout (4B units unless noted)
  int* counts = (int*)d_ws;                // NN (zeroed)
  float* sumbuf = (float*)d_ws + NN;       // 256 (zeroed)
  int* rowptr = (int*)d_ws + NN + 256;     // NN+1
  int* cursor = rowptr + NN + 1;           // NN
  int* elist = cursor + NN;                // NE
  size_t off = (size_t)(NN + 256 + (NN + 1) + NN + NE);
  off = (off + 3) & ~(size_t)3;            // 16B align
  u16* P1 = (u16*)((float*)d_ws + off);    // NN*128 u16
  u16* P2 = P1 + (size_t)NN * DD;          // NN*128 u16
  u16* Pv = P2 + (size_t)NN * DD;          // NN*128 u16
  float* ce = (float*)(Pv + (size_t)NN * DD);  // 128
  float* cv = ce + 128;                        // 128
  float* aggr = cv + 128;                      // NN*128 f32

  hipMemsetAsync(d_ws, 0, (size_t)(NN + 256) * 4, stream);
  k_const<<<1, 128, 0, stream>>>(u, We, be, Wv, bv, ce, cv);
  k_hist<<<NE / 256, 256, 0, stream>>>(receivers, counts);
  k_scan<<<1, 256, 0, stream>>>(counts, rowptr, cursor);
  k_fill<<<NE / 256, 256, 0, stream>>>(receivers, cursor, elist);
  k_nodeproj<<<dim3((NN + 63) / 64, 3), 256, 0, stream>>>(node_attr, We, Wv,
                                                           P1, P2, Pv);
  k_edge<<<NE / 64, 256, 0, stream>>>(edge_attr, We, receivers, senders, P1,
                                      P2, ce, e_out, sumbuf);
  k_aggr<<<NN, 128, 0, stream>>>(e_out, rowptr, elist, aggr);
  k_node<<<(NN + 63) / 64, 256, 0, stream>>>(aggr, Wv, Pv, cv, v_out,
                                             sumbuf + 128);
  k_global<<<1, 128, 0, stream>>>(sumbuf, u, Wu, bu, u_out);
}

// Round 3
// 570.312 us; speedup vs baseline: 1.3114x; 1.3114x over previous
//
#include <hip/hip_runtime.h>
#include <hip/hip_bf16.h>

// GN block on MI355X — FP32 I/O, bf16 MFMA internally.
//
// e_new = relu(edge@We0 + P1[recv] + P2[send] + ce)      (MFMA)
// aggr  = CSR gather-sum of e_new by receiver
// v_new = relu(aggr@Wv0 + Pv + cv)                        (MFMA)
// u_new = relu([mean_e, mean_v, u]@Wu + bu)
// P = node @ {We1,We2,Wv1} (MFMA), stored bf16 interleaved [n][384].
// Weights transposed+bf16 once into workspace (k_prep) so B-fragments are
// contiguous ds_read_b128.

#define NN 20000
#define NE 320000
#define DD 128
#define SAS 136  // LDS stride (u16) for A tile: pad 8 -> conflict-free b128
#define SBS 136  // LDS stride (u16) for B^T tile

typedef unsigned short u16;
typedef __attribute__((ext_vector_type(8))) short bf16x8;
typedef __attribute__((ext_vector_type(4))) float f32x4;

__device__ __forceinline__ float b2f(unsigned short h) {
  return __uint_as_float(((unsigned int)h) << 16);
}
__device__ __forceinline__ unsigned short f2b(float f) {
  unsigned int u = __float_as_uint(f);
  unsigned int r = (u + 0x7fffu + ((u >> 16) & 1u)) >> 16;  // RNE
  return (unsigned short)r;
}

// ---------------------------------------------------------------- constants
__global__ void k_const(const float* u, const float* We, const float* be,
                        const float* Wv, const float* bv, float* ce,
                        float* cv) {
  __shared__ float su[DD];
  int j = threadIdx.x;  // 128
  su[j] = u[j];
  __syncthreads();
  float a = be[j];
  float b = bv[j];
  for (int k = 0; k < DD; ++k) {
    a = fmaf(su[k], We[(384 + k) * DD + j], a);
    b = fmaf(su[k], Wv[(256 + k) * DD + j], b);
  }
  ce[j] = a;
  cv[j] = b;
}

// --------------------------------------- transpose+bf16 the 5 GEMM weights
// wt layout: 5 matrices of [n][k] bf16 128x128:
//   0: We rows 0:128 (edge)   1: We rows 128:256 (recv)
//   2: We rows 256:384 (send) 3: Wv rows 128:256 (Pv)   4: Wv rows 0:128
__global__ void k_prep(const float* We, const float* Wv, u16* wt) {
  int m = blockIdx.x;
  const float* W = (m == 0)   ? We
                   : (m == 1) ? We + 128 * DD
                   : (m == 2) ? We + 256 * DD
                   : (m == 3) ? Wv + 128 * DD
                              : Wv;
  u16* o = wt + (size_t)m * DD * DD;
  for (int i = threadIdx.x; i < DD * DD; i += 256) {
    int k = i >> 7, n = i & 127;
    o[n * DD + k] = f2b(W[i]);
  }
}

// ---------------------------------------------------------------- CSR build
__global__ void k_hist(const int* recv, int* counts) {
  int e = blockIdx.x * blockDim.x + threadIdx.x;
  if (e < NE) atomicAdd(&counts[recv[e]], 1);
}

__global__ void k_scan(const int* counts, int* rowptr, int* cursor) {
  __shared__ int wsum[16];
  __shared__ int carry;
  int tid = threadIdx.x;  // 1024
  int lane = tid & 63, wv = tid >> 6;
  if (tid == 0) carry = 0;
  __syncthreads();
  for (int base = 0; base < NN; base += 1024) {
    int i = base + tid;
    int v = (i < NN) ? counts[i] : 0;
    int x = v;
    for (int off = 1; off < 64; off <<= 1) {
      int t = __shfl_up(x, off);
      if (lane >= off) x += t;
    }
    if (lane == 63) wsum[wv] = x;
    __syncthreads();
    if (wv == 0 && lane < 16) {
      int y = wsum[lane];
      for (int off = 1; off < 16; off <<= 1) {
        int t = __shfl_up(y, off);
        if (lane >= off) y += t;
      }
      wsum[lane] = y;
    }
    __syncthreads();
    int woff = (wv > 0) ? wsum[wv - 1] : 0;
    int excl = carry + woff + (x - v);
    if (i < NN) {
      rowptr[i] = excl;
      cursor[i] = excl;
    }
    __syncthreads();
    if (tid == 0) carry += wsum[15];
    __syncthreads();
  }
  if (tid == 0) rowptr[NN] = carry;  // == NE
}

__global__ void k_fill(const int* recv, int* cursor, int* elist) {
  int e = blockIdx.x * blockDim.x + threadIdx.x;
  if (e < NE) {
    int slot = atomicAdd(&cursor[recv[e]], 1);
    elist[slot] = e;
  }
}

// --------------------------------------------------------- MFMA GEMM core
// sA [64][SAS] bf16, sBT [128][SBS] bf16 (B^T: [n][k]).
// Wave w computes rows 0..63 x cols [32w,32w+32): acc[mt][nt], m=mt*16+quad*4+r,
// n = w*32+nt*16+(lane&15).
__device__ __forceinline__ void mfma_core(const u16* sA, const u16* sBT,
                                          int lane, int w, f32x4 acc[4][2]) {
  int r15 = lane & 15;
  int koff = (lane >> 4) * 8;
#pragma unroll
  for (int k0 = 0; k0 < DD; k0 += 32) {
    bf16x8 a[4], b[2];
#pragma unroll
    for (int mt = 0; mt < 4; ++mt)
      a[mt] = *(const bf16x8*)&sA[(mt * 16 + r15) * SAS + k0 + koff];
#pragma unroll
    for (int nt = 0; nt < 2; ++nt)
      b[nt] = *(const bf16x8*)&sBT[(w * 32 + nt * 16 + r15) * SBS + k0 + koff];
#pragma unroll
    for (int mt = 0; mt < 4; ++mt)
#pragma unroll
      for (int nt = 0; nt < 2; ++nt)
        acc[mt][nt] = __builtin_amdgcn_mfma_f32_16x16x32_bf16(
            a[mt], b[nt], acc[mt][nt], 0, 0, 0);
  }
}

__device__ __forceinline__ void stage_w(u16* sBT, const u16* wsrc, int tid) {
  const uint4* ws = (const uint4*)wsrc;
  for (int i = tid; i < DD * DD / 8; i += 256) {
    int n = i >> 4, kk = (i & 15) * 8;
    *(uint4*)&sBT[n * SBS + kk] = ws[i];
  }
}

// ------------------------------------------------------------- edge block
__global__ __launch_bounds__(256) void k_edge(const float* edge_attr,
                                              const u16* wt, const int* recv,
                                              const int* send, const u16* P,
                                              const float* ce, float* e_out,
                                              float* sum_e) {
  __shared__ __align__(16) u16 sA[64 * SAS];
  __shared__ __align__(16) u16 sBT[DD * SBS];
  __shared__ int sRecv[64], sSend[64];
  __shared__ float sCol[DD];
  int tid = threadIdx.x;
  int e0 = blockIdx.x * 64;
  stage_w(sBT, wt, tid);  // We0^T
  const float4* src = (const float4*)(edge_attr + (size_t)e0 * DD);
  for (int i = tid; i < 64 * DD / 4; i += 256) {
    float4 a4 = src[i];
    int rr = i >> 5, cc = (i & 31) * 4;
    ushort4 h;
    h.x = f2b(a4.x); h.y = f2b(a4.y); h.z = f2b(a4.z); h.w = f2b(a4.w);
    *(ushort4*)&sA[rr * SAS + cc] = h;
  }
  if (tid < 64) {
    sRecv[tid] = recv[e0 + tid];
    sSend[tid] = send[e0 + tid];
  }
  if (tid < DD) sCol[tid] = 0.f;
  __syncthreads();
  int lane = tid & 63, w = tid >> 6;
  f32x4 acc[4][2] = {};
  mfma_core(sA, sBT, lane, w, acc);
  // epilogue straight from fragments
  int c15 = lane & 15, quad = lane >> 4;
  int col0 = w * 32 + c15, col1 = col0 + 16;
  float ce0 = ce[col0], ce1 = ce[col1];
  float cs0 = 0.f, cs1 = 0.f;
#pragma unroll
  for (int mt = 0; mt < 4; ++mt) {
#pragma unroll
    for (int r = 0; r < 4; ++r) {
      int m = mt * 16 + quad * 4 + r;
      int rc = sRecv[m], sd = sSend[m];
      const u16* p1 = &P[(size_t)rc * 384];
      const u16* p2 = &P[(size_t)sd * 384 + 128];
      float v0 = fmaxf(acc[mt][0][r] + b2f(p1[col0]) + b2f(p2[col0]) + ce0, 0.f);
      float v1 = fmaxf(acc[mt][1][r] + b2f(p1[col1]) + b2f(p2[col1]) + ce1, 0.f);
      size_t ob = (size_t)(e0 + m) * DD;
      e_out[ob + col0] = v0;
      e_out[ob + col1] = v1;
      cs0 += v0;
      cs1 += v1;
    }
  }
  atomicAdd(&sCol[col0], cs0);
  atomicAdd(&sCol[col1], cs1);
  __syncthreads();
  if (tid < DD) atomicAdd(&sum_e[tid], sCol[tid]);
}

// ----------------------------------------------- P = node @ {We1,We2,Wv1}
__global__ __launch_bounds__(256) void k_nodeproj(const float* node_attr,
                                                  const u16* wt, u16* P) {
  __shared__ __align__(16) u16 sA[64 * SAS];
  __shared__ __align__(16) u16 sBT[DD * SBS];
  int tid = threadIdx.x;
  int n0 = blockIdx.x * 64;
  int sel = blockIdx.y;  // 0:recv 1:send 2:Pv
  stage_w(sBT, wt + (size_t)(1 + sel) * DD * DD, tid);
  for (int i = tid; i < 64 * DD / 4; i += 256) {
    int rr = i >> 5, cc = (i & 31) * 4;
    float4 a4 = (n0 + rr < NN)
                    ? ((const float4*)node_attr)[(size_t)(n0 + rr) * 32 + (i & 31)]
                    : make_float4(0, 0, 0, 0);
    ushort4 h;
    h.x = f2b(a4.x); h.y = f2b(a4.y); h.z = f2b(a4.z); h.w = f2b(a4.w);
    *(ushort4*)&sA[rr * SAS + cc] = h;
  }
  __syncthreads();
  int lane = tid & 63, w = tid >> 6;
  f32x4 acc[4][2] = {};
  mfma_core(sA, sBT, lane, w, acc);
  int c15 = lane & 15, quad = lane >> 4;
  int col0 = w * 32 + c15, col1 = col0 + 16;
#pragma unroll
  for (int mt = 0; mt < 4; ++mt) {
#pragma unroll
    for (int r = 0; r < 4; ++r) {
      int n = n0 + mt * 16 + quad * 4 + r;
      if (n < NN) {
        u16* o = &P[(size_t)n * 384 + sel * 128];
        o[col0] = f2b(acc[mt][0][r]);
        o[col1] = f2b(acc[mt][1][r]);
      }
    }
  }
}

// ----------------------------------------------------- aggregation (CSR sum)
__global__ __launch_bounds__(256) void k_aggr(const float* e_new,
                                              const int* rowptr,
                                              const int* elist, float* aggr) {
  int tid = threadIdx.x;
  int wv = tid >> 6, lane = tid & 63;
  int n = blockIdx.x * 4 + wv;
  if (n >= NN) return;
  int b = rowptr[n], e = rowptr[n + 1];
  float sx = 0.f, sy = 0.f, tx = 0.f, ty = 0.f;
  int i = b;
  for (; i + 1 < e; i += 2) {
    int e1 = elist[i], e2 = elist[i + 1];
    float2 a = *(const float2*)&e_new[(size_t)e1 * DD + lane * 2];
    float2 c = *(const float2*)&e_new[(size_t)e2 * DD + lane * 2];
    sx += a.x; sy += a.y; tx += c.x; ty += c.y;
  }
  if (i < e) {
    float2 a = *(const float2*)&e_new[(size_t)elist[i] * DD + lane * 2];
    sx += a.x; sy += a.y;
  }
  float2 out;
  out.x = sx + tx;
  out.y = sy + ty;
  *(float2*)&aggr[(size_t)n * DD + lane * 2] = out;
}

// ------------------------------------------------------------- node block
__global__ __launch_bounds__(256) void k_node(const float* aggr, const u16* wt,
                                              const u16* P, const float* cv,
                                              float* v_out, float* sum_v) {
  __shared__ __align__(16) u16 sA[64 * SAS];
  __shared__ __align__(16) u16 sBT[DD * SBS];
  __shared__ float sCol[DD];
  int tid = threadIdx.x;
  int n0 = blockIdx.x * 64;
  stage_w(sBT, wt + (size_t)4 * DD * DD, tid);  // Wv0^T
  for (int i = tid; i < 64 * DD / 4; i += 256) {
    int rr = i >> 5, cc = (i & 31) * 4;
    float4 a4 = (n0 + rr < NN)
                    ? ((const float4*)aggr)[(size_t)(n0 + rr) * 32 + (i & 31)]
                    : make_float4(0, 0, 0, 0);
    ushort4 h;
    h.x = f2b(a4.x); h.y = f2b(a4.y); h.z = f2b(a4.z); h.w = f2b(a4.w);
    *(ushort4*)&sA[rr * SAS + cc] = h;
  }
  if (tid < DD) sCol[tid] = 0.f;
  __syncthreads();
  int lane = tid & 63, w = tid >> 6;
  f32x4 acc[4][2] = {};
  mfma_core(sA, sBT, lane, w, acc);
  int c15 = lane & 15, quad = lane >> 4;
  int col0 = w * 32 + c15, col1 = col0 + 16;
  float cv0 = cv[col0], cv1 = cv[col1];
  float cs0 = 0.f, cs1 = 0.f;
#pragma unroll
  for (int mt = 0; mt < 4; ++mt) {
#pragma unroll
    for (int r = 0; r < 4; ++r) {
      int n = n0 + mt * 16 + quad * 4 + r;
      if (n < NN) {
        const u16* pv = &P[(size_t)n * 384 + 256];
        float v0 = fmaxf(acc[mt][0][r] + b2f(pv[col0]) + cv0, 0.f);
        float v1 = fmaxf(acc[mt][1][r] + b2f(pv[col1]) + cv1, 0.f);
        size_t ob = (size_t)n * DD;
        v_out[ob + col0] = v0;
        v_out[ob + col1] = v1;
        cs0 += v0;
        cs1 += v1;
      }
    }
  }
  atomicAdd(&sCol[col0], cs0);
  atomicAdd(&sCol[col1], cs1);
  __syncthreads();
  if (tid < DD) atomicAdd(&sum_v[tid], sCol[tid]);
}

// ------------------------------------------------------------ global block
__global__ void k_global(const float* sumbuf, const float* u, const float* Wu,
                         const float* bu, float* out) {
  __shared__ float sin_[384];
  int j = threadIdx.x;  // 128
  sin_[j] = sumbuf[j] * (1.0f / (float)NE);
  sin_[128 + j] = sumbuf[128 + j] * (1.0f / (float)NN);
  sin_[256 + j] = u[j];
  __syncthreads();
  float a = bu[j];
  for (int k = 0; k < 384; ++k) a = fmaf(sin_[k], Wu[k * DD + j], a);
  out[j] = fmaxf(a, 0.f);
}

// ---------------------------------------------------------------- launcher
extern "C" void kernel_launch(void* const* d_in, const int* in_sizes, int n_in,
                              void* d_out, int out_size, void* d_ws,
                              size_t ws_size, hipStream_t stream) {
  const float* edge_attr = (const float*)d_in[0];
  const float* node_attr = (const float*)d_in[1];
  const float* u = (const float*)d_in[2];
  const int* senders = (const int*)d_in[3];
  const int* receivers = (const int*)d_in[4];
  const float* We = (const float*)d_in[5];
  const float* be = (const float*)d_in[6];
  const float* Wv = (const float*)d_in[7];
  const float* bv = (const float*)d_in[8];
  const float* Wu = (const float*)d_in[9];
  const float* bu = (const float*)d_in[10];

  float* e_out = (float*)d_out;
  float* v_out = e_out + (size_t)NE * DD;
  float* u_out = v_out + (size_t)NN * DD;

  // workspace layout (4B units)
  int* counts = (int*)d_ws;             // NN (zeroed)
  float* sumbuf = (float*)d_ws + NN;    // 256 (zeroed)
  int* rowptr = (int*)d_ws + NN + 256;  // NN+1
  int* cursor = rowptr + NN + 1;        // NN
  int* elist = cursor + NN;             // NE
  size_t off = (size_t)(NN + 256 + (NN + 1) + NN + NE);
  off = (off + 3) & ~(size_t)3;              // 16B align
  u16* wt = (u16*)((float*)d_ws + off);      // 5*128*128 u16
  u16* P = wt + (size_t)5 * DD * DD;         // NN*384 u16
  float* ce = (float*)(P + (size_t)NN * 384);  // 128
  float* cv = ce + 128;                        // 128
  float* aggr = cv + 128;                      // NN*128 f32

  hipMemsetAsync(d_ws, 0, (size_t)(NN + 256) * 4, stream);
  k_prep<<<5, 256, 0, stream>>>(We, Wv, wt);
  k_const<<<1, 128, 0, stream>>>(u, We, be, Wv, bv, ce, cv);
  k_hist<<<NE / 256, 256, 0, stream>>>(receivers, counts);
  k_scan<<<1, 1024, 0, stream>>>(counts, rowptr, cursor);
  k_fill<<<NE / 256, 256, 0, stream>>>(receivers, cursor, elist);
  k_nodeproj<<<dim3((NN + 63) / 64, 3), 256, 0, stream>>>(node_attr, wt, P);
  k_edge<<<NE / 64, 256, 0, stream>>>(edge_attr, wt, receivers, senders, P, ce,
                                      e_out, sumbuf);
  k_aggr<<<(NN + 3) / 4, 256, 0, stream>>>(e_out, rowptr, elist, aggr);
  k_node<<<(NN + 63) / 64, 256, 0, stream>>>(aggr, wt, P, cv, v_out,
                                             sumbuf + 128);
  k_global<<<1, 128, 0, stream>>>(sumbuf, u, Wu, bu, u_out);
}

// Round 4
// 519.259 us; speedup vs baseline: 1.4403x; 1.0983x over previous
//
#include <hip/hip_runtime.h>
#include <hip/hip_bf16.h>

// GN block on MI355X — FP32 I/O, bf16 MFMA internally, fused aggregation.
//
// e_new = relu(edge@We0 + P1[recv] + P2[send] + ce)   (MFMA, sorted-edge order)
// aggr  = segmented per-tile reduction + atomics (fused into k_edge)
// v_new = relu(aggr@Wv0 + Pv + cv)                    (MFMA)
// u_new = relu([mean_e, mean_v, u]@Wu + bu)
// P = node @ {We1,We2,Wv1} stored bf16 [n][384]. Weights bf16+transposed once.

#define NN 20000
#define NE 320000
#define DD 128
#define SAS 136  // LDS stride (u16), pad 8 -> conflict-free b128
#define SBS 136
#define NBLK 768     // persistent blocks for k_edge (3 per CU x 256)
#define NTILE 5000   // NE/64

typedef unsigned short u16;
typedef __attribute__((ext_vector_type(8))) short bf16x8;
typedef __attribute__((ext_vector_type(4))) float f32x4;

__device__ __forceinline__ float b2f(unsigned short h) {
  return __uint_as_float(((unsigned int)h) << 16);
}
__device__ __forceinline__ unsigned short f2b(float f) {
  unsigned int u = __float_as_uint(f);
  unsigned int r = (u + 0x7fffu + ((u >> 16) & 1u)) >> 16;  // RNE
  return (unsigned short)r;
}

// --------------------------------------------------------- MFMA GEMM core
__device__ __forceinline__ void mfma_core(const u16* sA, const u16* sBT,
                                          int lane, int w, f32x4 acc[4][2]) {
  int r15 = lane & 15;
  int koff = (lane >> 4) * 8;
#pragma unroll
  for (int k0 = 0; k0 < DD; k0 += 32) {
    bf16x8 a[4], b[2];
#pragma unroll
    for (int mt = 0; mt < 4; ++mt)
      a[mt] = *(const bf16x8*)&sA[(mt * 16 + r15) * SAS + k0 + koff];
#pragma unroll
    for (int nt = 0; nt < 2; ++nt)
      b[nt] = *(const bf16x8*)&sBT[(w * 32 + nt * 16 + r15) * SBS + k0 + koff];
#pragma unroll
    for (int mt = 0; mt < 4; ++mt)
#pragma unroll
      for (int nt = 0; nt < 2; ++nt)
        acc[mt][nt] = __builtin_amdgcn_mfma_f32_16x16x32_bf16(
            a[mt], b[nt], acc[mt][nt], 0, 0, 0);
  }
}

__device__ __forceinline__ void stage_w(u16* sBT, const u16* wsrc, int tid) {
  const uint4* ws = (const uint4*)wsrc;
  for (int i = tid; i < DD * DD / 8; i += 256) {
    int n = i >> 4, kk = (i & 15) * 8;
    *(uint4*)&sBT[n * SBS + kk] = ws[i];
  }
}

// --------------------------------------- setup: hist + weight prep + consts
__global__ __launch_bounds__(256) void k_setup(const int* recv, int* counts,
                                               const float* We, const float* Wv,
                                               const float* u, const float* be,
                                               const float* bv, u16* wt,
                                               float* ce, float* cv) {
  __shared__ float su[DD];
  int b = blockIdx.x, tid = threadIdx.x;
  if (b < 1250) {  // histogram (1250*256 == NE)
    atomicAdd(&counts[recv[b * 256 + tid]], 1);
  } else if (b < 1255) {  // transpose+bf16: 0:We0 1:We1 2:We2 3:Wv1 4:Wv0
    int m = b - 1250;
    const float* W = (m == 0)   ? We
                     : (m == 1) ? We + 128 * DD
                     : (m == 2) ? We + 256 * DD
                     : (m == 3) ? Wv + 128 * DD
                                : Wv;
    u16* o = wt + (size_t)m * DD * DD;
    for (int i = tid; i < DD * DD; i += 256) {
      int k = i >> 7, n = i & 127;
      o[n * DD + k] = f2b(W[i]);
    }
  } else {  // ce = u@We3+be, cv = u@Wv2+bv
    if (tid < DD) su[tid] = u[tid];
    __syncthreads();
    if (tid < DD) {
      float a = be[tid], c = bv[tid];
      for (int k = 0; k < DD; ++k) {
        a = fmaf(su[k], We[(384 + k) * DD + tid], a);
        c = fmaf(su[k], Wv[(256 + k) * DD + tid], c);
      }
      ce[tid] = a;
      cv[tid] = c;
    }
  }
}

// ---------------------------------------------------------------- CSR scan
__global__ void k_scan(const int* counts, int* rowptr, int* cursor) {
  __shared__ int wsum[16];
  __shared__ int carry;
  int tid = threadIdx.x;  // 1024
  int lane = tid & 63, wv = tid >> 6;
  if (tid == 0) carry = 0;
  __syncthreads();
  for (int base = 0; base < NN; base += 1024) {
    int i = base + tid;
    int v = (i < NN) ? counts[i] : 0;
    int x = v;
    for (int off = 1; off < 64; off <<= 1) {
      int t = __shfl_up(x, off);
      if (lane >= off) x += t;
    }
    if (lane == 63) wsum[wv] = x;
    __syncthreads();
    if (wv == 0 && lane < 16) {
      int y = wsum[lane];
      for (int off = 1; off < 16; off <<= 1) {
        int t = __shfl_up(y, off);
        if (lane >= off) y += t;
      }
      wsum[lane] = y;
    }
    __syncthreads();
    int woff = (wv > 0) ? wsum[wv - 1] : 0;
    int excl = carry + woff + (x - v);
    if (i < NN) {
      rowptr[i] = excl;
      cursor[i] = excl;
    }
    __syncthreads();
    if (tid == 0) carry += wsum[15];
    __syncthreads();
  }
  if (tid == 0) rowptr[NN] = carry;  // == NE
}

// ---------------------------------- mid: CSR fill + P = node @ {We1,We2,Wv1}
__global__ __launch_bounds__(256) void k_mid(const int* recv, int* cursor,
                                             int* elist, const float* node_attr,
                                             const u16* wt, u16* P) {
  __shared__ __align__(16) u16 sA[64 * SAS];
  __shared__ __align__(16) u16 sBT[DD * SBS];
  int b = blockIdx.x, tid = threadIdx.x;
  if (b < 1250) {  // fill
    int e = b * 256 + tid;
    int slot = atomicAdd(&cursor[recv[e]], 1);
    elist[slot] = e;
    return;
  }
  int n0 = (b - 1250) * 64;
  for (int i = tid; i < 64 * DD / 4; i += 256) {
    int rr = i >> 5, cc = (i & 31) * 4;
    float4 a4 = (n0 + rr < NN)
                    ? ((const float4*)node_attr)[(size_t)(n0 + rr) * 32 + (i & 31)]
                    : make_float4(0, 0, 0, 0);
    ushort4 h;
    h.x = f2b(a4.x); h.y = f2b(a4.y); h.z = f2b(a4.z); h.w = f2b(a4.w);
    *(ushort4*)&sA[rr * SAS + cc] = h;
  }
  int lane = tid & 63, w = tid >> 6;
  int c15 = lane & 15, quad = lane >> 4;
  int col0 = w * 32 + c15, col1 = col0 + 16;
  for (int sel = 0; sel < 3; ++sel) {
    __syncthreads();  // sA ready / prior sBT reads done
    stage_w(sBT, wt + (size_t)(1 + sel) * DD * DD, tid);
    __syncthreads();
    f32x4 acc[4][2] = {};
    mfma_core(sA, sBT, lane, w, acc);
#pragma unroll
    for (int mt = 0; mt < 4; ++mt)
#pragma unroll
      for (int r = 0; r < 4; ++r) {
        int n = n0 + mt * 16 + quad * 4 + r;
        if (n < NN) {
          u16* o = &P[(size_t)n * 384 + sel * 128];
          o[col0] = f2b(acc[mt][0][r]);
          o[col1] = f2b(acc[mt][1][r]);
        }
      }
  }
}

// ---------------------- edge block: persistent, pipelined, fused aggregation
__global__ __launch_bounds__(256) void k_edge(const float* edge_attr,
                                              const u16* wt, const int* elist,
                                              const int* recv, const int* send,
                                              const u16* P, const float* ce,
                                              float* e_out, float* aggr,
                                              float* sum_e) {
  __shared__ __align__(16) u16 sBT[DD * SBS];  // persists across tiles
  __shared__ __align__(16) u16 sAO[64 * SAS];  // A tile, then e_new (bf16)
  __shared__ int sEid[64], sRecv[64], sSend[64];
  int tid = threadIdx.x;
  int lane = tid & 63, w = tid >> 6;
  int r15 = lane & 15, quad = lane >> 4;
  int col0 = w * 32 + r15, col1 = col0 + 16;
  int myrow = tid >> 5;        // A-staging rows: myrow + 8j
  int mycol = (tid & 31) * 4;  // f32 col offset (float4 chunk)

  float4 areg[8];
  int eid8[8];
  int eidN = 0, rcN = 0, sdN = 0;
  int t = blockIdx.x;

  {  // prefetch tile t (HBM first), then stage weights (L2)
    int base = t * 64;
#pragma unroll
    for (int j = 0; j < 8; ++j) eid8[j] = elist[base + myrow + 8 * j];
    if (tid < 64) {
      eidN = elist[base + tid];
      rcN = recv[eidN];
      sdN = send[eidN];
    }
#pragma unroll
    for (int j = 0; j < 8; ++j)
      areg[j] = *(const float4*)&edge_attr[(size_t)eid8[j] * DD + mycol];
  }
  stage_w(sBT, wt, tid);  // We0^T
  float ce0 = ce[col0], ce1 = ce[col1];
  float colsum = 0.f;  // threads 0..127 own column tid
  bool first = true;

  for (; t < NTILE; t += NBLK) {
    if (!first) __syncthreads();  // prev walk/copy done -> sAO free
    first = false;
#pragma unroll
    for (int j = 0; j < 8; ++j) {
      ushort4 h;
      h.x = f2b(areg[j].x); h.y = f2b(areg[j].y);
      h.z = f2b(areg[j].z); h.w = f2b(areg[j].w);
      *(ushort4*)&sAO[(myrow + 8 * j) * SAS + mycol] = h;
    }
    if (tid < 64) {
      sEid[tid] = eidN;
      sRecv[tid] = rcN;
      sSend[tid] = sdN;
    }
    __syncthreads();  // sA/meta (and sBT on first iter) ready
    int tn = t + NBLK;
    if (tn < NTILE) {  // prefetch next tile during compute
      int base = tn * 64;
#pragma unroll
      for (int j = 0; j < 8; ++j) eid8[j] = elist[base + myrow + 8 * j];
      if (tid < 64) {
        eidN = elist[base + tid];
        rcN = recv[eidN];
        sdN = send[eidN];
      }
#pragma unroll
      for (int j = 0; j < 8; ++j)
        areg[j] = *(const float4*)&edge_attr[(size_t)eid8[j] * DD + mycol];
    }
    f32x4 acc[4][2] = {};
    mfma_core(sAO, sBT, lane, w, acc);
    float vv[4][2][4];
#pragma unroll
    for (int mt = 0; mt < 4; ++mt)
#pragma unroll
      for (int r = 0; r < 4; ++r) {
        int m = mt * 16 + quad * 4 + r;
        const u16* p1 = &P[(size_t)sRecv[m] * 384];
        const u16* p2 = &P[(size_t)sSend[m] * 384 + 128];
        vv[mt][0][r] =
            fmaxf(acc[mt][0][r] + b2f(p1[col0]) + b2f(p2[col0]) + ce0, 0.f);
        vv[mt][1][r] =
            fmaxf(acc[mt][1][r] + b2f(p1[col1]) + b2f(p2[col1]) + ce1, 0.f);
      }
    __syncthreads();  // all mfma reads of sAO done
    u16* sOutH = sAO;
#pragma unroll
    for (int mt = 0; mt < 4; ++mt)
#pragma unroll
      for (int r = 0; r < 4; ++r) {
        int m = mt * 16 + quad * 4 + r;
        sOutH[m * SAS + col0] = f2b(vv[mt][0][r]);
        sOutH[m * SAS + col1] = f2b(vv[mt][1][r]);
      }
    __syncthreads();  // sOutH ready
    if (tid < DD) {
      // waves 0-1: segmented column reduction (receiver-sorted slots)
      float run = 0.f;
      int prev = sRecv[0];
      for (int r = 0; r < 64; ++r) {
        int cur = sRecv[r];  // wave-uniform
        float v = b2f(sOutH[r * SAS + tid]);
        if (cur != prev) {
          atomicAdd(&aggr[(size_t)prev * DD + tid], run);
          run = 0.f;
          prev = cur;
        }
        run += v;
        colsum += v;
      }
      atomicAdd(&aggr[(size_t)prev * DD + tid], run);
    } else {
      // waves 2-3: coalesced e_out row writes
      int tt = tid - 128;
#pragma unroll
      for (int j = 0; j < 8; ++j) {
        int i = tt + 128 * j;
        int row = i >> 4, ch = (i & 15) * 8;
        uint4 q = *(const uint4*)&sOutH[row * SAS + ch];
        float4 f0, f1;
        f0.x = b2f((u16)(q.x & 0xffff)); f0.y = b2f((u16)(q.x >> 16));
        f0.z = b2f((u16)(q.y & 0xffff)); f0.w = b2f((u16)(q.y >> 16));
        f1.x = b2f((u16)(q.z & 0xffff)); f1.y = b2f((u16)(q.z >> 16));
        f1.z = b2f((u16)(q.w & 0xffff)); f1.w = b2f((u16)(q.w >> 16));
        float* dst = &e_out[(size_t)sEid[row] * DD + ch];
        *(float4*)dst = f0;
        *(float4*)(dst + 4) = f1;
      }
    }
  }
  if (tid < DD) atomicAdd(&sum_e[tid], colsum);
}

// ------------------------------------------------------------- node block
__global__ __launch_bounds__(256) void k_node(const float* aggr, const u16* wt,
                                              const u16* P, const float* cv,
                                              float* v_out, float* sum_v) {
  __shared__ __align__(16) u16 sA[64 * SAS];
  __shared__ __align__(16) u16 sBT[DD * SBS];
  __shared__ float sCol[DD];
  int tid = threadIdx.x;
  int n0 = blockIdx.x * 64;
  stage_w(sBT, wt + (size_t)4 * DD * DD, tid);  // Wv0^T
  for (int i = tid; i < 64 * DD / 4; i += 256) {
    int rr = i >> 5, cc = (i & 31) * 4;
    float4 a4 = (n0 + rr < NN)
                    ? ((const float4*)aggr)[(size_t)(n0 + rr) * 32 + (i & 31)]
                    : make_float4(0, 0, 0, 0);
    ushort4 h;
    h.x = f2b(a4.x); h.y = f2b(a4.y); h.z = f2b(a4.z); h.w = f2b(a4.w);
    *(ushort4*)&sA[rr * SAS + cc] = h;
  }
  if (tid < DD) sCol[tid] = 0.f;
  __syncthreads();
  int lane = tid & 63, w = tid >> 6;
  f32x4 acc[4][2] = {};
  mfma_core(sA, sBT, lane, w, acc);
  int c15 = lane & 15, quad = lane >> 4;
  int col0 = w * 32 + c15, col1 = col0 + 16;
  float cv0 = cv[col0], cv1 = cv[col1];
  float cs0 = 0.f, cs1 = 0.f;
#pragma unroll
  for (int mt = 0; mt < 4; ++mt)
#pragma unroll
    for (int r = 0; r < 4; ++r) {
      int n = n0 + mt * 16 + quad * 4 + r;
      if (n < NN) {
        const u16* pv = &P[(size_t)n * 384 + 256];
        float v0 = fmaxf(acc[mt][0][r] + b2f(pv[col0]) + cv0, 0.f);
        float v1 = fmaxf(acc[mt][1][r] + b2f(pv[col1]) + cv1, 0.f);
        size_t ob = (size_t)n * DD;
        v_out[ob + col0] = v0;
        v_out[ob + col1] = v1;
        cs0 += v0;
        cs1 += v1;
      }
    }
  atomicAdd(&sCol[col0], cs0);
  atomicAdd(&sCol[col1], cs1);
  __syncthreads();
  if (tid < DD) atomicAdd(&sum_v[tid], sCol[tid]);
}

// ------------------------------------------------------------ global block
__global__ void k_global(const float* sumbuf, const float* u, const float* Wu,
                         const float* bu, float* out) {
  __shared__ float sin_[384];
  int j = threadIdx.x;  // 128
  sin_[j] = sumbuf[j] * (1.0f / (float)NE);
  sin_[128 + j] = sumbuf[128 + j] * (1.0f / (float)NN);
  sin_[256 + j] = u[j];
  __syncthreads();
  float a = bu[j];
  for (int k = 0; k < 384; ++k) a = fmaf(sin_[k], Wu[k * DD + j], a);
  out[j] = fmaxf(a, 0.f);
}

// ---------------------------------------------------------------- launcher
extern "C" void kernel_launch(void* const* d_in, const int* in_sizes, int n_in,
                              void* d_out, int out_size, void* d_ws,
                              size_t ws_size, hipStream_t stream) {
  const float* edge_attr = (const float*)d_in[0];
  const float* node_attr = (const float*)d_in[1];
  const float* u = (const float*)d_in[2];
  const int* senders = (const int*)d_in[3];
  const int* receivers = (const int*)d_in[4];
  const float* We = (const float*)d_in[5];
  const float* be = (const float*)d_in[6];
  const float* Wv = (const float*)d_in[7];
  const float* bv = (const float*)d_in[8];
  const float* Wu = (const float*)d_in[9];
  const float* bu = (const float*)d_in[10];

  float* e_out = (float*)d_out;
  float* v_out = e_out + (size_t)NE * DD;
  float* u_out = v_out + (size_t)NN * DD;

  // workspace layout (4B units); [counts|sumbuf|aggr] zeroed in one memset
  int* counts = (int*)d_ws;                       // NN
  float* sumbuf = (float*)d_ws + NN;              // 256
  float* aggr = (float*)d_ws + NN + 256;          // NN*128 (16B-aligned)
  int* rowptr = (int*)d_ws + NN + 256 + NN * DD;  // NN+1
  int* cursor = rowptr + NN + 1;                  // NN
  int* elist = cursor + NN;                       // NE
  size_t off = (size_t)(NN + 256 + NN * DD + (NN + 1) + NN + NE);
  off = (off + 3) & ~(size_t)3;                // 16B align
  u16* wt = (u16*)((float*)d_ws + off);        // 5*128*128 u16
  u16* P = wt + (size_t)5 * DD * DD;           // NN*384 u16
  float* ce = (float*)(P + (size_t)NN * 384);  // 128
  float* cv = ce + 128;                        // 128

  hipMemsetAsync(d_ws, 0, (size_t)(NN + 256 + NN * DD) * 4, stream);
  k_setup<<<1256, 256, 0, stream>>>(receivers, counts, We, Wv, u, be, bv, wt,
                                    ce, cv);
  k_scan<<<1, 1024, 0, stream>>>(counts, rowptr, cursor);
  k_mid<<<1250 + 313, 256, 0, stream>>>(receivers, cursor, elist, node_attr,
                                        wt, P);
  k_edge<<<NBLK, 256, 0, stream>>>(edge_attr, wt, elist, receivers, senders, P,
                                   ce, e_out, aggr, sumbuf);
  k_node<<<(NN + 63) / 64, 256, 0, stream>>>(aggr, wt, P, cv, v_out,
                                             sumbuf + 128);
  k_global<<<1, 128, 0, stream>>>(sumbuf, u, Wu, bu, u_out);
}